// Round 1
// baseline (3175.700 us; speedup 1.0000x reference)
//
#include <hip/hip_runtime.h>
#include <cstdint>
#include <cstddef>

#define T_DIM 5
#define F_DIM 8
#define Z_DIM 16
#define Y_DIM 96
#define X_DIM 96
#define C_DIM 128
#define NRAYS 32768
#define K_SAMP 128

// input vol [B=1][F][T][Z][Y][X] strides (floats): f:737280 t:147456 z:9216 y:96 x:1
// vol_r [t][z][y][x][f] strides: t:1179648 z:73728 y:768 x:8 f:1

__global__ void init_minmax_kernel(unsigned* loU, unsigned* hiU) {
    int i = threadIdx.x;
    if (i < T_DIM) { loU[i] = 0x7F800000u; hiU[i] = 0u; }
}

__global__ void transpose_w_kernel(const float* __restrict__ w, float* __restrict__ wT) {
    int i = blockIdx.x * 256 + threadIdx.x;
    if (i >= C_DIM * C_DIM * 27) return;
    int co  = i / (C_DIM * 27);
    int r   = i % (C_DIM * 27);
    int ci  = r / 27;
    int tap = r % 27;
    wT[(tap * C_DIM + ci) * C_DIM + co] = w[i];
}

__global__ __launch_bounds__(256) void nearfar_kernel(
        const float* __restrict__ ro, const float* __restrict__ rd,
        float* __restrict__ nearA, float* __restrict__ farA,
        unsigned* loU, unsigned* hiU) {
    int gid = blockIdx.x * 256 + threadIdx.x;          // 0 .. T*NRAYS-1
    int t = gid / NRAYS;
    const float* o = ro + (size_t)gid * 3;
    const float* d = rd + (size_t)gid * 3;
    float ox = o[0], oy = o[1], oz = o[2];
    float dx = d[0], dy = d[1], dz = d[2];
    float t1x = (0.f - ox) / dx, t2x = (1.f - ox) / dx;
    float t1y = (0.f - oy) / dy, t2y = (1.f - oy) / dy;
    float t1z = (0.f - oz) / dz, t2z = (1.f - oz) / dz;
    float nr = fmaxf(fmaxf(fminf(t1x, t2x), fminf(t1y, t2y)), fminf(t1z, t2z));
    float fr = fminf(fminf(fmaxf(t1x, t2x), fmaxf(t1y, t2y)), fmaxf(t1z, t2z));
    nr = fmaxf(nr, 0.01f);
    fr = fmaxf(fr, nr + 1e-6f);
    nearA[gid] = nr;
    farA[gid]  = fr;
    float slast = fmaf(0.9921875f, fr - nr, nr);       // starts[:,127] = near + (127/128)*span
    // wave reduction (t is uniform within a wave: NRAYS % 64 == 0)
    float mn = nr, mx = slast;
    #pragma unroll
    for (int off = 32; off > 0; off >>= 1) {
        mn = fminf(mn, __shfl_down(mn, off, 64));
        mx = fmaxf(mx, __shfl_down(mx, off, 64));
    }
    if ((threadIdx.x & 63) == 0) {
        // positive floats: uint bit order == value order
        atomicMin(&loU[t], __float_as_uint(mn));
        atomicMax(&hiU[t], __float_as_uint(mx));
    }
}

__global__ __launch_bounds__(192) void conv_kernel(
        const float* __restrict__ xin, const float* __restrict__ wT,
        const float* __restrict__ bias, float* __restrict__ vol_r) {
    const int x = threadIdx.x;                       // 0..95
    const int y = blockIdx.z * 2 + threadIdx.y;      // 0..95
    const int t = blockIdx.y;                        // 0..4
    const int co_base = blockIdx.x * 8;              // 8 contiguous c_out per thread
    float acc[8];
    #pragma unroll
    for (int j = 0; j < 8; ++j) acc[j] = bias[co_base + j];

    for (int kt = 0; kt < 3; ++kt) {
        int tt = t + kt - 1;
        if (tt < 0 || tt >= T_DIM) continue;         // block-uniform
        for (int ky = 0; ky < 3; ++ky) {
            int yy = y + ky - 1;
            if (yy < 0 || yy >= Y_DIM) continue;
            for (int kx = 0; kx < 3; ++kx) {
                int xx = x + kx - 1;
                if (xx < 0 || xx >= X_DIM) continue;
                const int tap = (kt * 3 + ky) * 3 + kx;
                const float* wt = wT + (size_t)tap * (C_DIM * C_DIM) + co_base; // + ci*128
                const float* xp = xin + tt * 147456 + yy * 96 + xx;
                #pragma unroll
                for (int f = 0; f < 8; ++f) {
                    const float* xpf = xp + f * 737280;
                    #pragma unroll 4
                    for (int z = 0; z < 16; ++z) {
                        float v = xpf[z * 9216];
                        const float* wr = wt + (f * 16 + z) * C_DIM;  // uniform -> s_load
                        float4 wa = *(const float4*)(wr);
                        float4 wb = *(const float4*)(wr + 4);
                        acc[0] = fmaf(wa.x, v, acc[0]);
                        acc[1] = fmaf(wa.y, v, acc[1]);
                        acc[2] = fmaf(wa.z, v, acc[2]);
                        acc[3] = fmaf(wa.w, v, acc[3]);
                        acc[4] = fmaf(wb.x, v, acc[4]);
                        acc[5] = fmaf(wb.y, v, acc[5]);
                        acc[6] = fmaf(wb.z, v, acc[6]);
                        acc[7] = fmaf(wb.w, v, acc[7]);
                    }
                }
            }
        }
    }
    #pragma unroll
    for (int j = 0; j < 8; ++j) {
        int co = co_base + j;
        int f = co >> 4, z = co & 15;
        vol_r[((((size_t)t * Z_DIM + z) * Y_DIM + y) * X_DIM + x) * F_DIM + f] = acc[j];
    }
}

__global__ __launch_bounds__(256) void render_kernel(
        const float* __restrict__ ro, const float* __restrict__ rd,
        const float* __restrict__ vol_r,
        const float* __restrict__ nearA, const float* __restrict__ farA,
        const unsigned* __restrict__ loU, const unsigned* __restrict__ hiU,
        const float* __restrict__ dens_w, const float* __restrict__ dens_b,
        float* __restrict__ out) {
    int gid = blockIdx.x * 256 + threadIdx.x;
    int t = gid / NRAYS;
    const float* o = ro + (size_t)gid * 3;
    const float* d = rd + (size_t)gid * 3;
    float ox = o[0], oy = o[1], oz = o[2];
    float dx = d[0], dy = d[1], dz = d[2];
    float nr = nearA[gid], fr = farA[gid];
    float span = fr - nr;
    const float* vt = vol_r + (size_t)t * 1179648;
    float dw0 = dens_w[0], dw1 = dens_w[1], dw2 = dens_w[2], dw3 = dens_w[3];
    float dw4 = dens_w[4], dw5 = dens_w[5], dw6 = dens_w[6], dw7 = dens_w[7];
    float db = dens_b[0];

    float trans = 1.f, num = 0.f, den = 0.f;
    for (int k = 0; k < K_SAMP; ++k) {
        float b0 = (float)k * 0.0078125f;
        float b1 = (float)(k + 1) * 0.0078125f;
        float s  = fmaf(b0, span, nr);
        float e  = fmaf(b1, span, nr);
        float delta = e - s;
        float mid = 0.5f * (s + e);
        float px = fmaf(dx, mid, ox);
        float py = fmaf(dy, mid, oy);
        float pz = fmaf(dz, mid, oz);
        float gx = fminf(fmaxf(px, 0.f), 1.f) * 95.f;
        float gy = fminf(fmaxf(py, 0.f), 1.f) * 95.f;
        float gz = fminf(fmaxf(pz, 0.f), 1.f) * 15.f;
        int x0 = (int)gx, y0 = (int)gy, z0 = (int)gz;   // >=0, trunc == floor
        float fx = gx - (float)x0, fy = gy - (float)y0, fz = gz - (float)z0;
        int x1 = min(x0 + 1, 95), y1 = min(y0 + 1, 95), z1 = min(z0 + 1, 15);

        float a0 = 0.f, a1 = 0.f, a2 = 0.f, a3 = 0.f;
        float a4 = 0.f, a5 = 0.f, a6 = 0.f, a7 = 0.f;
        #pragma unroll
        for (int zz = 0; zz < 2; ++zz) {
            int zi = zz ? z1 : z0;
            float wz = zz ? fz : (1.f - fz);
            #pragma unroll
            for (int yy = 0; yy < 2; ++yy) {
                int yi = yy ? y1 : y0;
                float wzy = wz * (yy ? fy : (1.f - fy));
                const float* base = vt + ((size_t)(zi * 96 + yi) * 96) * 8;
                const float4* p0 = (const float4*)(base + (size_t)x0 * 8);
                const float4* p1 = (const float4*)(base + (size_t)x1 * 8);
                float4 c0a = p0[0], c0b = p0[1];
                float4 c1a = p1[0], c1b = p1[1];
                a0 = fmaf(wzy, c0a.x + fx * (c1a.x - c0a.x), a0);
                a1 = fmaf(wzy, c0a.y + fx * (c1a.y - c0a.y), a1);
                a2 = fmaf(wzy, c0a.z + fx * (c1a.z - c0a.z), a2);
                a3 = fmaf(wzy, c0a.w + fx * (c1a.w - c0a.w), a3);
                a4 = fmaf(wzy, c0b.x + fx * (c1b.x - c0b.x), a4);
                a5 = fmaf(wzy, c0b.y + fx * (c1b.y - c0b.y), a5);
                a6 = fmaf(wzy, c0b.z + fx * (c1b.z - c0b.z), a6);
                a7 = fmaf(wzy, c0b.w + fx * (c1b.w - c0b.w), a7);
            }
        }
        float pre = a0 * dw0 + a1 * dw1 + a2 * dw2 + a3 * dw3
                  + a4 * dw4 + a5 * dw5 + a6 * dw6 + a7 * dw7 + db;
        // softplus = logaddexp(pre, 0) = max(pre,0) + log1p(exp(-|pre|))
        float dens = fmaxf(pre, 0.f) + log1pf(expf(-fabsf(pre)));
        float dd = dens * delta;
        float ex = expf(-dd);
        float alpha = 1.f - ex;
        float w = alpha * trans;
        num = fmaf(w, s, num);
        den += w;
        trans *= ex;
    }
    float depth = num / (den + 1e-10f);
    float lo = __uint_as_float(loU[t]);
    float hi = __uint_as_float(hiU[t]);
    depth = fminf(fmaxf(depth, lo), hi);
    out[gid] = depth;
}

extern "C" void kernel_launch(void* const* d_in, const int* in_sizes, int n_in,
                              void* d_out, int out_size, void* d_ws, size_t ws_size,
                              hipStream_t stream) {
    const float* vol = (const float*)d_in[0];   // [1,8,5,16,96,96]
    const float* ro  = (const float*)d_in[1];   // [5,32768,3]
    const float* rd  = (const float*)d_in[2];   // [5,32768,3]
    const float* cw  = (const float*)d_in[3];   // [128,128,3,3,3]
    const float* cb  = (const float*)d_in[4];   // [128]
    const float* dw  = (const float*)d_in[5];   // [8,1]
    const float* dbp = (const float*)d_in[6];   // [1]
    float* out = (float*)d_out;                 // [5,32768,1] f32

    float* ws     = (float*)d_ws;
    float* vol_r  = ws;                         // 5,898,240 floats  [t][z][y][x][f]
    float* wT     = vol_r + 5898240;            // 442,368 floats    [tap][ci][co]
    float* nearA  = wT + 442368;                // 163,840
    float* farA   = nearA + 163840;             // 163,840
    unsigned* loU = (unsigned*)(farA + 163840); // 5 (+pad)
    unsigned* hiU = loU + 8;                    // 5

    hipLaunchKernelGGL(init_minmax_kernel, dim3(1), dim3(64), 0, stream, loU, hiU);
    hipLaunchKernelGGL(transpose_w_kernel, dim3(1728), dim3(256), 0, stream, cw, wT);
    hipLaunchKernelGGL(nearfar_kernel, dim3(640), dim3(256), 0, stream,
                       ro, rd, nearA, farA, loU, hiU);
    hipLaunchKernelGGL(conv_kernel, dim3(16, 5, 48), dim3(96, 2, 1), 0, stream,
                       vol, wT, cb, vol_r);
    hipLaunchKernelGGL(render_kernel, dim3(640), dim3(256), 0, stream,
                       ro, rd, vol_r, nearA, farA, loU, hiU, dw, dbp, out);
}

// Round 2
// 1014.733 us; speedup vs baseline: 3.1296x; 3.1296x over previous
//
#include <hip/hip_runtime.h>
#include <cstdint>
#include <cstddef>

#define T_DIM 5
#define F_DIM 8
#define Z_DIM 16
#define Y_DIM 96
#define X_DIM 96
#define C_DIM 128
#define NRAYS 32768
#define K_SAMP 128

// input vol [1][F=8][T=5][Z=16][Y=96][X=96] strides (floats): f:737280 t:147456 z:9216 y:96 x:1
// scalar field fld [t][z][y][x] strides: t:147456 z:9216 y:96 x:1  (2.95 MB total -> L2-resident)
// reduced weights wR [tap][ci=(f_in*16+z_in)][z_out] : 27*128*16 = 55296 floats

__global__ void init_minmax_kernel(unsigned* loU, unsigned* hiU) {
    int i = threadIdx.x;
    if (i < T_DIM) { loU[i] = 0x7F800000u; hiU[i] = 0u; }
}

// wR[tap][ci][z] = sum_f conv_w[(f*16+z)*128 + ci][tap] * dens_w[f]
// bR[z]         = sum_f conv_b[f*16+z] * dens_w[f]
__global__ void prep_w_kernel(const float* __restrict__ w, const float* __restrict__ cb,
                              const float* __restrict__ dw,
                              float* __restrict__ wR, float* __restrict__ bR) {
    int i = blockIdx.x * 256 + threadIdx.x;
    if (i < 27 * 128 * 16) {
        int tap = i >> 11;          // /2048
        int r   = i & 2047;
        int ci  = r >> 4;
        int z   = r & 15;
        float s = 0.f;
        #pragma unroll
        for (int f = 0; f < 8; ++f)
            s += w[(size_t)((f * 16 + z) * 128 + ci) * 27 + tap] * dw[f];
        wR[i] = s;
    }
    if (i < 16) {
        float s = 0.f;
        #pragma unroll
        for (int f = 0; f < 8; ++f) s += cb[f * 16 + i] * dw[f];
        bR[i] = s;
    }
}

__global__ __launch_bounds__(256) void nearfar_kernel(
        const float* __restrict__ ro, const float* __restrict__ rd,
        float* __restrict__ nearA, float* __restrict__ farA,
        unsigned* loU, unsigned* hiU) {
    int gid = blockIdx.x * 256 + threadIdx.x;          // 0 .. T*NRAYS-1
    int t = gid / NRAYS;
    const float* o = ro + (size_t)gid * 3;
    const float* d = rd + (size_t)gid * 3;
    float ox = o[0], oy = o[1], oz = o[2];
    float dx = d[0], dy = d[1], dz = d[2];
    float t1x = (0.f - ox) / dx, t2x = (1.f - ox) / dx;
    float t1y = (0.f - oy) / dy, t2y = (1.f - oy) / dy;
    float t1z = (0.f - oz) / dz, t2z = (1.f - oz) / dz;
    float nr = fmaxf(fmaxf(fminf(t1x, t2x), fminf(t1y, t2y)), fminf(t1z, t2z));
    float fr = fminf(fminf(fmaxf(t1x, t2x), fmaxf(t1y, t2y)), fmaxf(t1z, t2z));
    nr = fmaxf(nr, 0.01f);
    fr = fmaxf(fr, nr + 1e-6f);
    nearA[gid] = nr;
    farA[gid]  = fr;
    float slast = fmaf(0.9921875f, fr - nr, nr);       // starts[:,127]
    float mn = nr, mx = slast;
    #pragma unroll
    for (int off = 32; off > 0; off >>= 1) {
        mn = fminf(mn, __shfl_down(mn, off, 64));
        mx = fmaxf(mx, __shfl_down(mx, off, 64));
    }
    if ((threadIdx.x & 63) == 0) {
        atomicMin(&loU[t], __float_as_uint(mn));   // positive floats: bit order == value order
        atomicMax(&hiU[t], __float_as_uint(mx));
    }
}

// block (96,2,2): x, y-sub, f-split(2x4 feats). 192 threads per f-split group -> tz wave-uniform
// grid (48, 5): y-pair, t
__global__ __launch_bounds__(384) void conv_kernel(
        const float* __restrict__ xin, const float* __restrict__ wR,
        const float* __restrict__ bR, float* __restrict__ fld) {
    const int x  = threadIdx.x;                  // 0..95
    const int ty = threadIdx.y;                  // 0..1
    const int fs = threadIdx.z;                  // 0..1 (wave-uniform: 192-thread groups)
    const int y  = blockIdx.x * 2 + ty;          // 0..95
    const int t  = blockIdx.y;                   // 0..4

    float acc[16];
    #pragma unroll
    for (int z = 0; z < 16; ++z) acc[z] = 0.f;

    for (int kt = 0; kt < 3; ++kt) {
        int tt = t + kt - 1;
        if (tt < 0 || tt >= T_DIM) continue;             // block-uniform
        for (int ky = 0; ky < 3; ++ky) {
            int yy = y + ky - 1;
            if (yy < 0 || yy >= Y_DIM) continue;         // wave-uniform
            for (int kx = 0; kx < 3; ++kx) {
                int xx = x + kx - 1;
                if (xx < 0 || xx >= X_DIM) continue;     // divergent only at lanes 0/95
                const int tap = (kt * 3 + ky) * 3 + kx;
                #pragma unroll
                for (int fi = 0; fi < 4; ++fi) {
                    const int f = fs * 4 + fi;
                    const float* xp = xin + (size_t)f * 737280 + tt * 147456 + yy * 96 + xx;
                    const float* wp = wR + (size_t)(tap * 128 + f * 16) * 16;   // + zi*16
                    #pragma unroll
                    for (int zi = 0; zi < 16; ++zi) {
                        float v = xp[(size_t)zi * 9216];
                        const float* wr = wp + zi * 16;          // wave-uniform -> s_load
                        float4 w0 = *(const float4*)(wr);
                        float4 w1 = *(const float4*)(wr + 4);
                        float4 w2 = *(const float4*)(wr + 8);
                        float4 w3 = *(const float4*)(wr + 12);
                        acc[0]  = fmaf(w0.x, v, acc[0]);
                        acc[1]  = fmaf(w0.y, v, acc[1]);
                        acc[2]  = fmaf(w0.z, v, acc[2]);
                        acc[3]  = fmaf(w0.w, v, acc[3]);
                        acc[4]  = fmaf(w1.x, v, acc[4]);
                        acc[5]  = fmaf(w1.y, v, acc[5]);
                        acc[6]  = fmaf(w1.z, v, acc[6]);
                        acc[7]  = fmaf(w1.w, v, acc[7]);
                        acc[8]  = fmaf(w2.x, v, acc[8]);
                        acc[9]  = fmaf(w2.y, v, acc[9]);
                        acc[10] = fmaf(w2.z, v, acc[10]);
                        acc[11] = fmaf(w2.w, v, acc[11]);
                        acc[12] = fmaf(w3.x, v, acc[12]);
                        acc[13] = fmaf(w3.y, v, acc[13]);
                        acc[14] = fmaf(w3.z, v, acc[14]);
                        acc[15] = fmaf(w3.w, v, acc[15]);
                    }
                }
            }
        }
    }

    __shared__ float red[2][96][16];   // fs==1 partials, 12 KB
    if (fs == 1) {
        #pragma unroll
        for (int z = 0; z < 16; ++z) red[ty][x][z] = acc[z];
    }
    __syncthreads();
    if (fs == 0) {
        #pragma unroll
        for (int z = 0; z < 16; ++z) {
            float v = acc[z] + red[ty][x][z] + bR[z];
            fld[(((size_t)t * Z_DIM + z) * Y_DIM + y) * X_DIM + x] = v;
        }
    }
}

__global__ __launch_bounds__(256) void render_kernel(
        const float* __restrict__ ro, const float* __restrict__ rd,
        const float* __restrict__ fld,
        const float* __restrict__ nearA, const float* __restrict__ farA,
        const unsigned* __restrict__ loU, const unsigned* __restrict__ hiU,
        const float* __restrict__ dens_b, float* __restrict__ out) {
    int gid = blockIdx.x * 256 + threadIdx.x;
    int t = gid / NRAYS;
    const float* o = ro + (size_t)gid * 3;
    const float* d = rd + (size_t)gid * 3;
    float ox = o[0], oy = o[1], oz = o[2];
    float dx = d[0], dy = d[1], dz = d[2];
    float nr = nearA[gid], fr = farA[gid];
    float span = fr - nr;
    const float* vt = fld + (size_t)t * 147456;
    float db = dens_b[0];

    float trans = 1.f, num = 0.f, den = 0.f;
    #pragma unroll 2
    for (int k = 0; k < K_SAMP; ++k) {
        float b0 = (float)k * 0.0078125f;
        float b1 = (float)(k + 1) * 0.0078125f;
        float s  = fmaf(b0, span, nr);
        float e  = fmaf(b1, span, nr);
        float delta = e - s;
        float mid = 0.5f * (s + e);
        float px = fmaf(dx, mid, ox);
        float py = fmaf(dy, mid, oy);
        float pz = fmaf(dz, mid, oz);
        float gx = fminf(fmaxf(px, 0.f), 1.f) * 95.f;
        float gy = fminf(fmaxf(py, 0.f), 1.f) * 95.f;
        float gz = fminf(fmaxf(pz, 0.f), 1.f) * 15.f;
        // clamp base so that +1 neighbor is always in-bounds; frac>1 is exact lerp to the edge
        int x0 = min((int)gx, 94), y0 = min((int)gy, 94), z0 = min((int)gz, 14);
        float fx = gx - (float)x0, fy = gy - (float)y0, fz = gz - (float)z0;

        const float* base = vt + (size_t)z0 * 9216 + (size_t)y0 * 96 + x0;
        float c000 = base[0],        c001 = base[1];
        float c010 = base[96],       c011 = base[97];
        float c100 = base[9216],     c101 = base[9217];
        float c110 = base[9312],     c111 = base[9313];

        float v00 = c000 + fx * (c001 - c000);
        float v01 = c010 + fx * (c011 - c010);
        float v10 = c100 + fx * (c101 - c100);
        float v11 = c110 + fx * (c111 - c110);
        float v0  = v00 + fy * (v01 - v00);
        float v1  = v10 + fy * (v11 - v10);
        float pre = v0 + fz * (v1 - v0) + db;

        // softplus = max(x,0) + log1p(exp(-|x|))
        float dens = fmaxf(pre, 0.f) + log1pf(expf(-fabsf(pre)));
        float dd = dens * delta;
        float ex = expf(-dd);
        float alpha = 1.f - ex;
        float w = alpha * trans;
        num = fmaf(w, s, num);
        den += w;
        trans *= ex;
    }
    float depth = num / (den + 1e-10f);
    float lo = __uint_as_float(loU[t]);
    float hi = __uint_as_float(hiU[t]);
    depth = fminf(fmaxf(depth, lo), hi);
    out[gid] = depth;
}

extern "C" void kernel_launch(void* const* d_in, const int* in_sizes, int n_in,
                              void* d_out, int out_size, void* d_ws, size_t ws_size,
                              hipStream_t stream) {
    const float* vol = (const float*)d_in[0];   // [1,8,5,16,96,96]
    const float* ro  = (const float*)d_in[1];   // [5,32768,3]
    const float* rd  = (const float*)d_in[2];   // [5,32768,3]
    const float* cw  = (const float*)d_in[3];   // [128,128,3,3,3]
    const float* cb  = (const float*)d_in[4];   // [128]
    const float* dw  = (const float*)d_in[5];   // [8,1]
    const float* dbp = (const float*)d_in[6];   // [1]
    float* out = (float*)d_out;                 // [5,32768,1] f32

    float* ws     = (float*)d_ws;
    float* fld    = ws;                         // 737,280 floats  [t][z][y][x]
    float* wR     = fld + 737280;               // 55,296 floats   [tap][ci][z_out]
    float* bR     = wR + 55296;                 // 16 (+pad to 32)
    float* nearA  = bR + 32;                    // 163,840
    float* farA   = nearA + 163840;             // 163,840
    unsigned* loU = (unsigned*)(farA + 163840); // 5 (+pad)
    unsigned* hiU = loU + 8;                    // 5

    hipLaunchKernelGGL(init_minmax_kernel, dim3(1), dim3(64), 0, stream, loU, hiU);
    hipLaunchKernelGGL(prep_w_kernel, dim3(216), dim3(256), 0, stream, cw, cb, dw, wR, bR);
    hipLaunchKernelGGL(nearfar_kernel, dim3(640), dim3(256), 0, stream,
                       ro, rd, nearA, farA, loU, hiU);
    hipLaunchKernelGGL(conv_kernel, dim3(48, 5), dim3(96, 2, 2), 0, stream,
                       vol, wR, bR, fld);
    hipLaunchKernelGGL(render_kernel, dim3(640), dim3(256), 0, stream,
                       ro, rd, fld, nearA, farA, loU, hiU, dbp, out);
}

// Round 3
// 552.700 us; speedup vs baseline: 5.7458x; 1.8360x over previous
//
#include <hip/hip_runtime.h>
#include <cstdint>
#include <cstddef>

#define T_DIM 5
#define F_DIM 8
#define Z_DIM 16
#define Y_DIM 96
#define X_DIM 96
#define NRAYS 32768
#define K_SAMP 128

// input vol [1][F=8][T=5][Z=16][Y=96][X=96] strides (floats): f:737280 t:147456 z:9216 y:96 x:1
// scalar field fld [t][z][y][x] strides: t:147456 z:9216 y:96 x:1  (2.95 MB -> L2-resident)
// reduced weights wR [tap][ci=(f_in*16+z_in)][z_out] : 27*128*16 = 55296 floats
// conv partials part[s=0..3][t][z][y][x] (f-pair splits)

__global__ void init_minmax_kernel(unsigned* loU, unsigned* hiU) {
    int i = threadIdx.x;
    if (i < T_DIM) { loU[i] = 0x7F800000u; hiU[i] = 0u; }
}

// wR[tap][ci][z] = sum_f conv_w[(f*16+z)*128 + ci][tap] * dens_w[f]
// bR[z]         = sum_f conv_b[f*16+z] * dens_w[f]
__global__ void prep_w_kernel(const float* __restrict__ w, const float* __restrict__ cb,
                              const float* __restrict__ dw,
                              float* __restrict__ wR, float* __restrict__ bR) {
    int i = blockIdx.x * 256 + threadIdx.x;
    if (i < 27 * 128 * 16) {
        int tap = i >> 11;
        int r   = i & 2047;
        int ci  = r >> 4;
        int z   = r & 15;
        float s = 0.f;
        #pragma unroll
        for (int f = 0; f < 8; ++f)
            s += w[(size_t)((f * 16 + z) * 128 + ci) * 27 + tap] * dw[f];
        wR[i] = s;
    }
    if (i < 16) {
        float s = 0.f;
        #pragma unroll
        for (int f = 0; f < 8; ++f) s += cb[f * 16 + i] * dw[f];
        bR[i] = s;
    }
}

__global__ __launch_bounds__(256) void nearfar_kernel(
        const float* __restrict__ ro, const float* __restrict__ rd,
        float* __restrict__ nearA, float* __restrict__ farA,
        unsigned* loU, unsigned* hiU) {
    int gid = blockIdx.x * 256 + threadIdx.x;          // 0 .. T*NRAYS-1
    int t = gid / NRAYS;
    const float* o = ro + (size_t)gid * 3;
    const float* d = rd + (size_t)gid * 3;
    float ox = o[0], oy = o[1], oz = o[2];
    float dx = d[0], dy = d[1], dz = d[2];
    float t1x = (0.f - ox) / dx, t2x = (1.f - ox) / dx;
    float t1y = (0.f - oy) / dy, t2y = (1.f - oy) / dy;
    float t1z = (0.f - oz) / dz, t2z = (1.f - oz) / dz;
    float nr = fmaxf(fmaxf(fminf(t1x, t2x), fminf(t1y, t2y)), fminf(t1z, t2z));
    float fr = fminf(fminf(fmaxf(t1x, t2x), fmaxf(t1y, t2y)), fmaxf(t1z, t2z));
    nr = fmaxf(nr, 0.01f);
    fr = fmaxf(fr, nr + 1e-6f);
    nearA[gid] = nr;
    farA[gid]  = fr;
    float slast = fmaf(0.9921875f, fr - nr, nr);       // starts[:,127]
    float mn = nr, mx = slast;
    #pragma unroll
    for (int off = 32; off > 0; off >>= 1) {
        mn = fminf(mn, __shfl_down(mn, off, 64));
        mx = fmaxf(mx, __shfl_down(mx, off, 64));
    }
    if ((threadIdx.x & 63) == 0) {
        atomicMin(&loU[t], __float_as_uint(mn));   // positive floats: bit order == value order
        atomicMax(&hiU[t], __float_as_uint(mx));
    }
}

// grid (48, 5, 4): y-pair, t, f-pair split.  block (96,2).
__global__ __launch_bounds__(192) void conv_kernel(
        const float* __restrict__ xin, const float* __restrict__ wR,
        float* __restrict__ part) {
    const int x  = threadIdx.x;                  // 0..95
    const int ty = threadIdx.y;                  // 0..1
    const int y  = blockIdx.x * 2 + ty;          // 0..95
    const int t  = blockIdx.y;                   // 0..4
    const int fs = blockIdx.z;                   // 0..3 -> feats {2fs, 2fs+1}

    float acc[16];
    #pragma unroll
    for (int z = 0; z < 16; ++z) acc[z] = 0.f;

    for (int kt = 0; kt < 3; ++kt) {
        int tt = t + kt - 1;
        if (tt < 0 || tt >= T_DIM) continue;             // block-uniform
        for (int ky = 0; ky < 3; ++ky) {
            int yy = y + ky - 1;
            if (yy < 0 || yy >= Y_DIM) continue;
            for (int kx = 0; kx < 3; ++kx) {
                int xx = x + kx - 1;
                if (xx < 0 || xx >= X_DIM) continue;     // divergent only at lanes 0/95
                const int tap = (kt * 3 + ky) * 3 + kx;
                #pragma unroll
                for (int fi = 0; fi < 2; ++fi) {
                    const int f = fs * 2 + fi;
                    const float* xp = xin + (size_t)f * 737280 + tt * 147456 + yy * 96 + xx;
                    // batch the 16 independent gathers first -> 16-deep MLP
                    float v[16];
                    #pragma unroll
                    for (int zi = 0; zi < 16; ++zi) v[zi] = xp[(size_t)zi * 9216];
                    const float* wp = wR + (size_t)(tap * 128 + f * 16) * 16;
                    #pragma unroll
                    for (int zi = 0; zi < 16; ++zi) {
                        const float* wr = wp + zi * 16;          // loop-uniform -> s_load
                        float4 w0 = *(const float4*)(wr);
                        float4 w1 = *(const float4*)(wr + 4);
                        float4 w2 = *(const float4*)(wr + 8);
                        float4 w3 = *(const float4*)(wr + 12);
                        float v0 = v[zi];
                        acc[0]  = fmaf(w0.x, v0, acc[0]);
                        acc[1]  = fmaf(w0.y, v0, acc[1]);
                        acc[2]  = fmaf(w0.z, v0, acc[2]);
                        acc[3]  = fmaf(w0.w, v0, acc[3]);
                        acc[4]  = fmaf(w1.x, v0, acc[4]);
                        acc[5]  = fmaf(w1.y, v0, acc[5]);
                        acc[6]  = fmaf(w1.z, v0, acc[6]);
                        acc[7]  = fmaf(w1.w, v0, acc[7]);
                        acc[8]  = fmaf(w2.x, v0, acc[8]);
                        acc[9]  = fmaf(w2.y, v0, acc[9]);
                        acc[10] = fmaf(w2.z, v0, acc[10]);
                        acc[11] = fmaf(w2.w, v0, acc[11]);
                        acc[12] = fmaf(w3.x, v0, acc[12]);
                        acc[13] = fmaf(w3.y, v0, acc[13]);
                        acc[14] = fmaf(w3.z, v0, acc[14]);
                        acc[15] = fmaf(w3.w, v0, acc[15]);
                    }
                }
            }
        }
    }
    float* po = part + (size_t)fs * 737280;
    #pragma unroll
    for (int z = 0; z < 16; ++z)
        po[(((size_t)t * Z_DIM + z) * Y_DIM + y) * X_DIM + x] = acc[z];
}

// fld = sum of 4 partials + bias[z], float4-vectorized. 737280/4 = 184320 float4s.
__global__ __launch_bounds__(256) void combine_kernel(
        const float* __restrict__ part, const float* __restrict__ bR,
        float* __restrict__ fld) {
    int i = blockIdx.x * 256 + threadIdx.x;
    if (i >= 184320) return;
    int z = (i / 2304) & 15;                 // (i*4 / 9216) % 16 ; same z across the float4
    float b = bR[z];
    const float4* p0 = (const float4*)part;
    const float4* p1 = p0 + 184320;
    const float4* p2 = p1 + 184320;
    const float4* p3 = p2 + 184320;
    float4 a = p0[i], c = p1[i], d = p2[i], e = p3[i];
    float4 r;
    r.x = a.x + c.x + d.x + e.x + b;
    r.y = a.y + c.y + d.y + e.y + b;
    r.z = a.z + c.z + d.z + e.z + b;
    r.w = a.w + c.w + d.w + e.w + b;
    ((float4*)fld)[i] = r;
}

// 4 lanes per ray, 32 samples each; transmittance chained across chunks via quad shuffles.
__global__ __launch_bounds__(256) void render_kernel(
        const float* __restrict__ ro, const float* __restrict__ rd,
        const float* __restrict__ fld,
        const float* __restrict__ nearA, const float* __restrict__ farA,
        const unsigned* __restrict__ loU, const unsigned* __restrict__ hiU,
        const float* __restrict__ dens_b, float* __restrict__ out) {
    int g = blockIdx.x * 256 + threadIdx.x;    // 0 .. 4*T*NRAYS-1
    int ray = g >> 2;
    int c = g & 3;
    int t = ray >> 15;                         // ray / NRAYS
    const float* o = ro + (size_t)ray * 3;
    const float* d = rd + (size_t)ray * 3;
    float ox = o[0], oy = o[1], oz = o[2];
    float dx = d[0], dy = d[1], dz = d[2];
    float nr = nearA[ray], fr = farA[ray];
    float span = fr - nr;
    const float* vt = fld + (size_t)t * 147456;
    float db = dens_b[0];

    float trans = 1.f, num = 0.f, den = 0.f, A = 0.f;
    const int k0 = c * 32;
    for (int kk = 0; kk < 32; ++kk) {
        int k = k0 + kk;
        float b0 = (float)k * 0.0078125f;
        float b1 = (float)(k + 1) * 0.0078125f;
        float s  = fmaf(b0, span, nr);
        float e  = fmaf(b1, span, nr);
        float delta = e - s;
        float mid = 0.5f * (s + e);
        float px = fmaf(dx, mid, ox);
        float py = fmaf(dy, mid, oy);
        float pz = fmaf(dz, mid, oz);
        float gx = fminf(fmaxf(px, 0.f), 1.f) * 95.f;
        float gy = fminf(fmaxf(py, 0.f), 1.f) * 95.f;
        float gz = fminf(fmaxf(pz, 0.f), 1.f) * 15.f;
        int x0 = min((int)gx, 94), y0 = min((int)gy, 94), z0 = min((int)gz, 14);
        float fx = gx - (float)x0, fy = gy - (float)y0, fz = gz - (float)z0;

        const float* base = vt + (size_t)z0 * 9216 + (size_t)y0 * 96 + x0;
        float c000 = base[0],        c001 = base[1];
        float c010 = base[96],       c011 = base[97];
        float c100 = base[9216],     c101 = base[9217];
        float c110 = base[9312],     c111 = base[9313];

        float v00 = c000 + fx * (c001 - c000);
        float v01 = c010 + fx * (c011 - c010);
        float v10 = c100 + fx * (c101 - c100);
        float v11 = c110 + fx * (c111 - c110);
        float v0  = v00 + fy * (v01 - v00);
        float v1  = v10 + fy * (v11 - v10);
        float pre = v0 + fz * (v1 - v0) + db;

        float dens = fmaxf(pre, 0.f) + log1pf(expf(-fabsf(pre)));   // softplus
        float dd = dens * delta;
        float ex = expf(-dd);
        float alpha = 1.f - ex;
        float w = alpha * trans;
        num = fmaf(w, s, num);
        den += w;
        trans *= ex;
        A += dd;
    }
    // prefix transmittance across the 4 chunks of this ray
    int lane = threadIdx.x & 63;
    int q = lane & ~3;
    float A0 = __shfl(A, q,     64);
    float A1 = __shfl(A, q + 1, 64);
    float A2 = __shfl(A, q + 2, 64);
    float P = 0.f;
    if (c > 0) P += A0;
    if (c > 1) P += A1;
    if (c > 2) P += A2;
    float sc = expf(-P);
    float numc = num * sc;
    float denc = den * sc;
    numc += __shfl_xor(numc, 1, 64);
    numc += __shfl_xor(numc, 2, 64);
    denc += __shfl_xor(denc, 1, 64);
    denc += __shfl_xor(denc, 2, 64);
    if (c == 0) {
        float depth = numc / (denc + 1e-10f);
        float lo = __uint_as_float(loU[t]);
        float hi = __uint_as_float(hiU[t]);
        depth = fminf(fmaxf(depth, lo), hi);
        out[ray] = depth;
    }
}

extern "C" void kernel_launch(void* const* d_in, const int* in_sizes, int n_in,
                              void* d_out, int out_size, void* d_ws, size_t ws_size,
                              hipStream_t stream) {
    const float* vol = (const float*)d_in[0];   // [1,8,5,16,96,96]
    const float* ro  = (const float*)d_in[1];   // [5,32768,3]
    const float* rd  = (const float*)d_in[2];   // [5,32768,3]
    const float* cw  = (const float*)d_in[3];   // [128,128,3,3,3]
    const float* cb  = (const float*)d_in[4];   // [128]
    const float* dw  = (const float*)d_in[5];   // [8,1]
    const float* dbp = (const float*)d_in[6];   // [1]
    float* out = (float*)d_out;                 // [5,32768,1] f32

    float* ws     = (float*)d_ws;
    float* fld    = ws;                         // 737,280
    float* part   = fld + 737280;               // 4 * 737,280
    float* wR     = part + 4 * 737280;          // 55,296
    float* bR     = wR + 55296;                 // 16 (+pad to 32)
    float* nearA  = bR + 32;                    // 163,840
    float* farA   = nearA + 163840;             // 163,840
    unsigned* loU = (unsigned*)(farA + 163840); // 5 (+pad)
    unsigned* hiU = loU + 8;                    // 5

    hipLaunchKernelGGL(init_minmax_kernel, dim3(1), dim3(64), 0, stream, loU, hiU);
    hipLaunchKernelGGL(prep_w_kernel, dim3(216), dim3(256), 0, stream, cw, cb, dw, wR, bR);
    hipLaunchKernelGGL(nearfar_kernel, dim3(640), dim3(256), 0, stream,
                       ro, rd, nearA, farA, loU, hiU);
    hipLaunchKernelGGL(conv_kernel, dim3(48, 5, 4), dim3(96, 2), 0, stream,
                       vol, wR, part);
    hipLaunchKernelGGL(combine_kernel, dim3(720), dim3(256), 0, stream, part, bR, fld);
    hipLaunchKernelGGL(render_kernel, dim3(2560), dim3(256), 0, stream,
                       ro, rd, fld, nearA, farA, loU, hiU, dbp, out);
}

// Round 4
// 351.944 us; speedup vs baseline: 9.0233x; 1.5704x over previous
//
#include <hip/hip_runtime.h>
#include <hip/hip_fp16.h>
#include <cstdint>
#include <cstddef>

#define T_DIM 5
#define F_DIM 8
#define Z_DIM 16
#define Y_DIM 96
#define X_DIM 96
#define NRAYS 32768
#define K_SAMP 128

// input vol [1][F=8][T=5][Z=16][Y=96][X=96] strides (floats): f:737280 t:147456 z:9216 y:96 x:1
// fld  f32  [t][z][y][x]                      (2.95 MB)
// fldp half2[t][z][y][x] = (fld[x],fld[x+1])  (2.95 MB -> per-XCD L2-resident)
// wR [tap][ci=(f*16+z_in)][z_out]: 27*128*16 = 55296 floats
// part[s][t][z][y][x], s = kt*4+fs (SK=12) or fs (SK=4)

__global__ void init_minmax_kernel(unsigned* loU, unsigned* hiU) {
    int i = threadIdx.x;
    if (i < T_DIM) { loU[i] = 0x7F800000u; hiU[i] = 0u; }
}

__global__ void prep_w_kernel(const float* __restrict__ w, const float* __restrict__ cb,
                              const float* __restrict__ dw,
                              float* __restrict__ wR, float* __restrict__ bR) {
    int i = blockIdx.x * 256 + threadIdx.x;
    if (i < 27 * 128 * 16) {
        int tap = i >> 11;
        int r   = i & 2047;
        int ci  = r >> 4;
        int z   = r & 15;
        float s = 0.f;
        #pragma unroll
        for (int f = 0; f < 8; ++f)
            s += w[(size_t)((f * 16 + z) * 128 + ci) * 27 + tap] * dw[f];
        wR[i] = s;
    }
    if (i < 16) {
        float s = 0.f;
        #pragma unroll
        for (int f = 0; f < 8; ++f) s += cb[f * 16 + i] * dw[f];
        bR[i] = s;
    }
}

__global__ __launch_bounds__(256) void nearfar_kernel(
        const float* __restrict__ ro, const float* __restrict__ rd,
        float* __restrict__ nearA, float* __restrict__ farA,
        unsigned* loU, unsigned* hiU) {
    int gid = blockIdx.x * 256 + threadIdx.x;          // 0 .. T*NRAYS-1
    int t = gid / NRAYS;
    const float* o = ro + (size_t)gid * 3;
    const float* d = rd + (size_t)gid * 3;
    float ox = o[0], oy = o[1], oz = o[2];
    float dx = d[0], dy = d[1], dz = d[2];
    float t1x = (0.f - ox) / dx, t2x = (1.f - ox) / dx;
    float t1y = (0.f - oy) / dy, t2y = (1.f - oy) / dy;
    float t1z = (0.f - oz) / dz, t2z = (1.f - oz) / dz;
    float nr = fmaxf(fmaxf(fminf(t1x, t2x), fminf(t1y, t2y)), fminf(t1z, t2z));
    float fr = fminf(fminf(fmaxf(t1x, t2x), fmaxf(t1y, t2y)), fmaxf(t1z, t2z));
    nr = fmaxf(nr, 0.01f);
    fr = fmaxf(fr, nr + 1e-6f);
    nearA[gid] = nr;
    farA[gid]  = fr;
    float slast = fmaf(0.9921875f, fr - nr, nr);       // starts[:,127]
    float mn = nr, mx = slast;
    #pragma unroll
    for (int off = 32; off > 0; off >>= 1) {
        mn = fminf(mn, __shfl_down(mn, off, 64));
        mx = fmaxf(mx, __shfl_down(mx, off, 64));
    }
    if ((threadIdx.x & 63) == 0) {
        atomicMin(&loU[t], __float_as_uint(mn));   // positive floats: bit order == value order
        atomicMax(&hiU[t], __float_as_uint(mx));
    }
}

// KTS==1: kt fixed from blockIdx.z (SK=12, full occupancy). KTS==3: kt loop (SK=4 fallback).
template<int KTS>
__global__ __launch_bounds__(192) void conv_kernel(
        const float* __restrict__ xin, const float* __restrict__ wR,
        float* __restrict__ part) {
    const int x  = threadIdx.x;                  // 0..95
    const int ty = threadIdx.y;                  // 0..1
    const int y  = blockIdx.x * 2 + ty;          // 0..95
    const int t  = blockIdx.y;                   // 0..4
    const int s  = blockIdx.z;                   // SK=12: kt*4+fs ; SK=4: fs
    const int fs = s & 3;
    const int kt_lo = (KTS == 1) ? (s >> 2)     : 0;
    const int kt_hi = (KTS == 1) ? (s >> 2) + 1 : 3;

    float acc[16];
    #pragma unroll
    for (int z = 0; z < 16; ++z) acc[z] = 0.f;

    for (int kt = kt_lo; kt < kt_hi; ++kt) {
        int tt = t + kt - 1;
        if (tt < 0 || tt >= T_DIM) continue;             // block-uniform
        for (int ky = 0; ky < 3; ++ky) {
            int yy = y + ky - 1;
            if (yy < 0 || yy >= Y_DIM) continue;
            for (int kx = 0; kx < 3; ++kx) {
                int xx = x + kx - 1;
                if (xx < 0 || xx >= X_DIM) continue;     // divergent only at lanes 0/95
                const int tap = (kt * 3 + ky) * 3 + kx;
                #pragma unroll
                for (int fi = 0; fi < 2; ++fi) {
                    const int f = fs * 2 + fi;
                    const float* xp = xin + (size_t)f * 737280 + tt * 147456 + yy * 96 + xx;
                    float v[16];                         // batch 16 gathers -> deep MLP
                    #pragma unroll
                    for (int zi = 0; zi < 16; ++zi) v[zi] = xp[(size_t)zi * 9216];
                    const float* wp = wR + (size_t)(tap * 128 + f * 16) * 16;
                    #pragma unroll
                    for (int zi = 0; zi < 16; ++zi) {
                        const float* wr = wp + zi * 16;
                        float4 w0 = *(const float4*)(wr);
                        float4 w1 = *(const float4*)(wr + 4);
                        float4 w2 = *(const float4*)(wr + 8);
                        float4 w3 = *(const float4*)(wr + 12);
                        float v0 = v[zi];
                        acc[0]  = fmaf(w0.x, v0, acc[0]);
                        acc[1]  = fmaf(w0.y, v0, acc[1]);
                        acc[2]  = fmaf(w0.z, v0, acc[2]);
                        acc[3]  = fmaf(w0.w, v0, acc[3]);
                        acc[4]  = fmaf(w1.x, v0, acc[4]);
                        acc[5]  = fmaf(w1.y, v0, acc[5]);
                        acc[6]  = fmaf(w1.z, v0, acc[6]);
                        acc[7]  = fmaf(w1.w, v0, acc[7]);
                        acc[8]  = fmaf(w2.x, v0, acc[8]);
                        acc[9]  = fmaf(w2.y, v0, acc[9]);
                        acc[10] = fmaf(w2.z, v0, acc[10]);
                        acc[11] = fmaf(w2.w, v0, acc[11]);
                        acc[12] = fmaf(w3.x, v0, acc[12]);
                        acc[13] = fmaf(w3.y, v0, acc[13]);
                        acc[14] = fmaf(w3.z, v0, acc[14]);
                        acc[15] = fmaf(w3.w, v0, acc[15]);
                    }
                }
            }
        }
    }
    float* po = part + (size_t)s * 737280;
    #pragma unroll
    for (int z = 0; z < 16; ++z)
        po[(((size_t)t * Z_DIM + z) * Y_DIM + y) * X_DIM + x] = acc[z];
}

// fld = sum of SK partials + bias[z]. 184320 float4 groups.
__global__ __launch_bounds__(256) void combine_kernel(
        const float* __restrict__ part, const float* __restrict__ bR,
        float* __restrict__ fld, int SK) {
    int i = blockIdx.x * 256 + threadIdx.x;
    if (i >= 184320) return;
    int z = (i / 2304) & 15;                 // same z across the 4 elems (9216%4==0)
    float b = bR[z];
    float4 r = make_float4(b, b, b, b);
    const float4* p = (const float4*)part;
    for (int s = 0; s < SK; ++s) {
        float4 a = p[(size_t)s * 184320 + i];
        r.x += a.x; r.y += a.y; r.z += a.z; r.w += a.w;
    }
    ((float4*)fld)[i] = r;
}

// fldp[i] = (half(fld[i]), half(fld[i+1])). Entries at x==95 are never read.
__global__ __launch_bounds__(256) void pack_kernel(
        const float* __restrict__ fld, __half2* __restrict__ fldp) {
    int i = blockIdx.x * 256 + threadIdx.x;
    if (i >= 737280) return;
    float a = fld[i];
    float b = fld[i + 1];    // 1-elem overrun at the very end lands in owned ws, unused
    fldp[i] = __floats2half2_rn(a, b);
}

// 4 lanes per ray, 32 samples each; transmittance chained across chunks via quad shuffles.
__global__ __launch_bounds__(256) void render_kernel(
        const float* __restrict__ ro, const float* __restrict__ rd,
        const __half2* __restrict__ fldp,
        const float* __restrict__ nearA, const float* __restrict__ farA,
        const unsigned* __restrict__ loU, const unsigned* __restrict__ hiU,
        const float* __restrict__ dens_b, float* __restrict__ out) {
    int g = blockIdx.x * 256 + threadIdx.x;    // 0 .. 4*T*NRAYS-1
    int ray = g >> 2;
    int c = g & 3;
    int t = ray >> 15;                         // ray / NRAYS
    const float* o = ro + (size_t)ray * 3;
    const float* d = rd + (size_t)ray * 3;
    float ox = o[0], oy = o[1], oz = o[2];
    float dx = d[0], dy = d[1], dz = d[2];
    float nr = nearA[ray], fr = farA[ray];
    float span = fr - nr;
    const __half2* vt = fldp + (size_t)t * 147456;
    float db = dens_b[0];

    float trans = 1.f, num = 0.f, den = 0.f, A = 0.f;
    int pidx = -1;
    float2 f00 = {0.f, 0.f}, f01 = {0.f, 0.f}, f10 = {0.f, 0.f}, f11 = {0.f, 0.f};
    const int k0 = c * 32;
    for (int kk = 0; kk < 32; ++kk) {
        int k = k0 + kk;
        float b0 = (float)k * 0.0078125f;
        float b1 = (float)(k + 1) * 0.0078125f;
        float s  = fmaf(b0, span, nr);
        float e  = fmaf(b1, span, nr);
        float delta = e - s;
        float mid = 0.5f * (s + e);
        float px = fmaf(dx, mid, ox);
        float py = fmaf(dy, mid, oy);
        float pz = fmaf(dz, mid, oz);
        float gx = fminf(fmaxf(px, 0.f), 1.f) * 95.f;
        float gy = fminf(fmaxf(py, 0.f), 1.f) * 95.f;
        float gz = fminf(fmaxf(pz, 0.f), 1.f) * 15.f;
        int x0 = min((int)gx, 94), y0 = min((int)gy, 94), z0 = min((int)gz, 14);
        float fx = gx - (float)x0, fy = gy - (float)y0, fz = gz - (float)z0;

        int idx = z0 * 9216 + y0 * 96 + x0;
        if (idx != pidx) {                    // exec-masked reload: ~2x fewer L2 requests
            pidx = idx;
            __half2 h00 = vt[idx];
            __half2 h01 = vt[idx + 96];
            __half2 h10 = vt[idx + 9216];
            __half2 h11 = vt[idx + 9312];
            f00 = __half22float2(h00);
            f01 = __half22float2(h01);
            f10 = __half22float2(h10);
            f11 = __half22float2(h11);
        }

        float v00 = f00.x + fx * (f00.y - f00.x);
        float v01 = f01.x + fx * (f01.y - f01.x);
        float v10 = f10.x + fx * (f10.y - f10.x);
        float v11 = f11.x + fx * (f11.y - f11.x);
        float v0  = v00 + fy * (v01 - v00);
        float v1  = v10 + fy * (v11 - v10);
        float pre = v0 + fz * (v1 - v0) + db;

        float u = __expf(-fabsf(pre));
        float dens = fmaxf(pre, 0.f) + __logf(1.f + u);   // softplus
        float dd = dens * delta;
        float ex = __expf(-dd);
        float alpha = 1.f - ex;
        float w = alpha * trans;
        num = fmaf(w, s, num);
        den += w;
        trans *= ex;
        A += dd;
    }
    // prefix transmittance across the 4 chunks of this ray
    int lane = threadIdx.x & 63;
    int q = lane & ~3;
    float A0 = __shfl(A, q,     64);
    float A1 = __shfl(A, q + 1, 64);
    float A2 = __shfl(A, q + 2, 64);
    float P = 0.f;
    if (c > 0) P += A0;
    if (c > 1) P += A1;
    if (c > 2) P += A2;
    float sc = __expf(-P);
    float numc = num * sc;
    float denc = den * sc;
    numc += __shfl_xor(numc, 1, 64);
    numc += __shfl_xor(numc, 2, 64);
    denc += __shfl_xor(denc, 1, 64);
    denc += __shfl_xor(denc, 2, 64);
    if (c == 0) {
        float depth = numc / (denc + 1e-10f);
        float lo = __uint_as_float(loU[t]);
        float hi = __uint_as_float(hiU[t]);
        depth = fminf(fmaxf(depth, lo), hi);
        out[ray] = depth;
    }
}

extern "C" void kernel_launch(void* const* d_in, const int* in_sizes, int n_in,
                              void* d_out, int out_size, void* d_ws, size_t ws_size,
                              hipStream_t stream) {
    const float* vol = (const float*)d_in[0];   // [1,8,5,16,96,96]
    const float* ro  = (const float*)d_in[1];   // [5,32768,3]
    const float* rd  = (const float*)d_in[2];   // [5,32768,3]
    const float* cw  = (const float*)d_in[3];   // [128,128,3,3,3]
    const float* cb  = (const float*)d_in[4];   // [128]
    const float* dw  = (const float*)d_in[5];   // [8,1]
    const float* dbp = (const float*)d_in[6];   // [1]
    float* out = (float*)d_out;                 // [5,32768,1] f32

    // choose conv split count by available workspace
    const size_t base_floats = 737280ull /*fld*/ + 737280ull /*fldp*/ + 55296 + 32
                             + 163840 + 163840 + 16;
    const int SK = (ws_size >= (base_floats + 12ull * 737280) * 4) ? 12 : 4;

    float* ws      = (float*)d_ws;
    float* fld     = ws;                          // 737,280
    __half2* fldp  = (__half2*)(fld + 737280);    // 737,280 half2 (= 737,280 f32 slots)
    float* part    = (float*)(fldp + 737280);     // SK * 737,280
    float* wR      = part + (size_t)SK * 737280;  // 55,296
    float* bR      = wR + 55296;                  // 16 (+pad to 32)
    float* nearA   = bR + 32;                     // 163,840
    float* farA    = nearA + 163840;              // 163,840
    unsigned* loU  = (unsigned*)(farA + 163840);  // 5 (+pad)
    unsigned* hiU  = loU + 8;                     // 5

    hipLaunchKernelGGL(init_minmax_kernel, dim3(1), dim3(64), 0, stream, loU, hiU);
    hipLaunchKernelGGL(prep_w_kernel, dim3(216), dim3(256), 0, stream, cw, cb, dw, wR, bR);
    hipLaunchKernelGGL(nearfar_kernel, dim3(640), dim3(256), 0, stream,
                       ro, rd, nearA, farA, loU, hiU);
    if (SK == 12) {
        hipLaunchKernelGGL(conv_kernel<1>, dim3(48, 5, 12), dim3(96, 2), 0, stream,
                           vol, wR, part);
    } else {
        hipLaunchKernelGGL(conv_kernel<3>, dim3(48, 5, 4), dim3(96, 2), 0, stream,
                           vol, wR, part);
    }
    hipLaunchKernelGGL(combine_kernel, dim3(720), dim3(256), 0, stream, part, bR, fld, SK);
    hipLaunchKernelGGL(pack_kernel, dim3(2880), dim3(256), 0, stream, fld, fldp);
    hipLaunchKernelGGL(render_kernel, dim3(2560), dim3(256), 0, stream,
                       ro, rd, fldp, nearA, farA, loU, hiU, dbp, out);
}

// Round 5
// 229.603 us; speedup vs baseline: 13.8312x; 1.5328x over previous
//
#include <hip/hip_runtime.h>
#include <hip/hip_fp16.h>
#include <cstdint>
#include <cstddef>

#define T_DIM 5
#define F_DIM 8
#define Z_DIM 16
#define Y_DIM 96
#define X_DIM 96
#define NRAYS 32768
#define K_SAMP 128

// vol   [1][F=8][T=5][Z=16][Y=96][X=96]  strides: f:737280 t:147456 z:9216 y:96 x:1
// volT  [f][t][y][x][z0..15]             (z-contiguous, 23.6 MB) -- dead after conv
// fld   f32 [t][z][y][x]                 (2.95 MB)               -- overlaps dead volT
// cellp Cell[t][z][y][x] 16 B = 8 corner halves                  -- overlaps dead volT
// wR [tap][ci=(f*16+z_in)][z_out]: 27*128*16
// part[s][t][z][y][x], s = kt*4+fs (SK=12) or fs (SK=4)

struct __align__(16) Cell { __half2 h0, h1, h2, h3; };
// h0=(c000,c001) z0y0(x,x+1); h1=(c010,c011) z0y1; h2=(c100,c101) z1y0; h3=(c110,c111) z1y1

__global__ void prep_w_kernel(const float* __restrict__ w, const float* __restrict__ cb,
                              const float* __restrict__ dw,
                              float* __restrict__ wR, float* __restrict__ bR,
                              unsigned* loU, unsigned* hiU) {
    int i = blockIdx.x * 256 + threadIdx.x;
    if (i < 8) { loU[i] = 0x7F800000u; hiU[i] = 0u; }
    if (i < 27 * 128 * 16) {
        int tap = i >> 11;
        int r   = i & 2047;
        int ci  = r >> 4;
        int z   = r & 15;
        float s = 0.f;
        #pragma unroll
        for (int f = 0; f < 8; ++f)
            s += w[(size_t)((f * 16 + z) * 128 + ci) * 27 + tap] * dw[f];
        wR[i] = s;
    }
    if (i < 16) {
        float s = 0.f;
        #pragma unroll
        for (int f = 0; f < 8; ++f) s += cb[f * 16 + i] * dw[f];
        bR[i] = s;
    }
}

// volT[(((f*5+t)*96+y)*96+x)*16 + z] = vol[f][t][z][y][x]
__global__ __launch_bounds__(256) void transpose_vol_kernel(
        const float* __restrict__ xin, float* __restrict__ volT) {
    int gid = blockIdx.x * 256 + threadIdx.x;          // 0 .. 368639  (f,t,y,x)
    if (gid >= 8 * 5 * 96 * 96) return;
    int x = gid % 96;
    int r = gid / 96;
    int y = r % 96;
    int r2 = r / 96;
    int t = r2 % 5;
    int f = r2 / 5;
    const float* src = xin + (size_t)f * 737280 + t * 147456 + y * 96 + x;
    float v[16];
    #pragma unroll
    for (int z = 0; z < 16; ++z) v[z] = src[(size_t)z * 9216];
    float4* dst = (float4*)(volT + (size_t)gid * 16);
    dst[0] = make_float4(v[0], v[1], v[2], v[3]);
    dst[1] = make_float4(v[4], v[5], v[6], v[7]);
    dst[2] = make_float4(v[8], v[9], v[10], v[11]);
    dst[3] = make_float4(v[12], v[13], v[14], v[15]);
}

__global__ __launch_bounds__(256) void nearfar_kernel(
        const float* __restrict__ ro, const float* __restrict__ rd,
        float* __restrict__ nearA, float* __restrict__ farA,
        unsigned* loU, unsigned* hiU) {
    int gid = blockIdx.x * 256 + threadIdx.x;          // 0 .. T*NRAYS-1
    int t = gid / NRAYS;                               // block-uniform (128 blocks per t)
    const float* o = ro + (size_t)gid * 3;
    const float* d = rd + (size_t)gid * 3;
    float ox = o[0], oy = o[1], oz = o[2];
    float dx = d[0], dy = d[1], dz = d[2];
    float t1x = (0.f - ox) / dx, t2x = (1.f - ox) / dx;
    float t1y = (0.f - oy) / dy, t2y = (1.f - oy) / dy;
    float t1z = (0.f - oz) / dz, t2z = (1.f - oz) / dz;
    float nr = fmaxf(fmaxf(fminf(t1x, t2x), fminf(t1y, t2y)), fminf(t1z, t2z));
    float fr = fminf(fminf(fmaxf(t1x, t2x), fmaxf(t1y, t2y)), fmaxf(t1z, t2z));
    nr = fmaxf(nr, 0.01f);
    fr = fmaxf(fr, nr + 1e-6f);
    nearA[gid] = nr;
    farA[gid]  = fr;
    float slast = fmaf(0.9921875f, fr - nr, nr);       // starts[:,127]
    float mn = nr, mx = slast;
    #pragma unroll
    for (int off = 32; off > 0; off >>= 1) {
        mn = fminf(mn, __shfl_down(mn, off, 64));
        mx = fmaxf(mx, __shfl_down(mx, off, 64));
    }
    __shared__ float smn[4], smx[4];
    int w = threadIdx.x >> 6;
    if ((threadIdx.x & 63) == 0) { smn[w] = mn; smx[w] = mx; }
    __syncthreads();
    if (threadIdx.x == 0) {
        mn = fminf(fminf(smn[0], smn[1]), fminf(smn[2], smn[3]));
        mx = fmaxf(fmaxf(smx[0], smx[1]), fmaxf(smx[2], smx[3]));
        atomicMin(&loU[t], __float_as_uint(mn));   // positive floats: bit order == value order
        atomicMax(&hiU[t], __float_as_uint(mx));
    }
}

#define FMA16(VV, WPTR) { \
    float4 w0 = *(const float4*)(WPTR); \
    float4 w1 = *(const float4*)((WPTR) + 4); \
    float4 w2 = *(const float4*)((WPTR) + 8); \
    float4 w3 = *(const float4*)((WPTR) + 12); \
    acc[0]  = fmaf(w0.x, VV, acc[0]);  acc[1]  = fmaf(w0.y, VV, acc[1]); \
    acc[2]  = fmaf(w0.z, VV, acc[2]);  acc[3]  = fmaf(w0.w, VV, acc[3]); \
    acc[4]  = fmaf(w1.x, VV, acc[4]);  acc[5]  = fmaf(w1.y, VV, acc[5]); \
    acc[6]  = fmaf(w1.z, VV, acc[6]);  acc[7]  = fmaf(w1.w, VV, acc[7]); \
    acc[8]  = fmaf(w2.x, VV, acc[8]);  acc[9]  = fmaf(w2.y, VV, acc[9]); \
    acc[10] = fmaf(w2.z, VV, acc[10]); acc[11] = fmaf(w2.w, VV, acc[11]); \
    acc[12] = fmaf(w3.x, VV, acc[12]); acc[13] = fmaf(w3.y, VV, acc[13]); \
    acc[14] = fmaf(w3.z, VV, acc[14]); acc[15] = fmaf(w3.w, VV, acc[15]); }

// KTS==1: kt fixed from blockIdx.z (SK=12). KTS==3: kt loop (SK=4 fallback).
template<int KTS>
__global__ __launch_bounds__(192) void conv_kernel(
        const float* __restrict__ volT, const float* __restrict__ wR,
        float* __restrict__ part) {
    const int x  = threadIdx.x;                  // 0..95
    const int ty = threadIdx.y;                  // 0..1
    const int y  = blockIdx.x * 2 + ty;          // 0..95
    const int t  = blockIdx.y;                   // 0..4
    const int s  = blockIdx.z;                   // SK=12: kt*4+fs ; SK=4: fs
    const int fs = s & 3;
    const int kt_lo = (KTS == 1) ? (s >> 2)     : 0;
    const int kt_hi = (KTS == 1) ? (s >> 2) + 1 : 3;

    float acc[16];
    #pragma unroll
    for (int z = 0; z < 16; ++z) acc[z] = 0.f;

    for (int kt = kt_lo; kt < kt_hi; ++kt) {
        int tt = t + kt - 1;
        if (tt < 0 || tt >= T_DIM) continue;             // block-uniform
        for (int ky = 0; ky < 3; ++ky) {
            int yy = y + ky - 1;
            if (yy < 0 || yy >= Y_DIM) continue;
            for (int kx = 0; kx < 3; ++kx) {
                int xx = x + kx - 1;
                if (xx < 0 || xx >= X_DIM) continue;     // divergent only at lanes 0/95
                const int tap = (kt * 3 + ky) * 3 + kx;
                #pragma unroll
                for (int fi = 0; fi < 2; ++fi) {
                    const int f = fs * 2 + fi;
                    const float4* vp = (const float4*)(volT +
                        ((((size_t)f * T_DIM + tt) * 96 + yy) * 96 + xx) * 16);
                    float4 va = vp[0], vb = vp[1], vc = vp[2], vd = vp[3];
                    const float* wp = wR + (size_t)(tap * 128 + f * 16) * 16;
                    FMA16(va.x, wp);        FMA16(va.y, wp + 16);
                    FMA16(va.z, wp + 32);   FMA16(va.w, wp + 48);
                    FMA16(vb.x, wp + 64);   FMA16(vb.y, wp + 80);
                    FMA16(vb.z, wp + 96);   FMA16(vb.w, wp + 112);
                    FMA16(vc.x, wp + 128);  FMA16(vc.y, wp + 144);
                    FMA16(vc.z, wp + 160);  FMA16(vc.w, wp + 176);
                    FMA16(vd.x, wp + 192);  FMA16(vd.y, wp + 208);
                    FMA16(vd.z, wp + 224);  FMA16(vd.w, wp + 240);
                }
            }
        }
    }
    float* po = part + (size_t)s * 737280;
    #pragma unroll
    for (int z = 0; z < 16; ++z)
        po[(((size_t)t * Z_DIM + z) * Y_DIM + y) * X_DIM + x] = acc[z];
}

// fld = sum of SK partials + bias[z]. 184320 float4 groups.
__global__ __launch_bounds__(256) void combine_kernel(
        const float* __restrict__ part, const float* __restrict__ bR,
        float* __restrict__ fld, int SK) {
    int i = blockIdx.x * 256 + threadIdx.x;
    if (i >= 184320) return;
    int z = (i / 2304) & 15;
    float b = bR[z];
    float4 r = make_float4(b, b, b, b);
    const float4* p = (const float4*)part;
    for (int s = 0; s < SK; ++s) {
        float4 a = p[(size_t)s * 184320 + i];
        r.x += a.x; r.y += a.y; r.z += a.z; r.w += a.w;
    }
    ((float4*)fld)[i] = r;
}

// cellp[t][z][y][x] = 8 fp16 corners of cell (z..z+1, y..y+1, x..x+1), clamped at edges.
__global__ __launch_bounds__(256) void pack_kernel(
        const float* __restrict__ fld, Cell* __restrict__ cellp) {
    int i = blockIdx.x * 256 + threadIdx.x;
    if (i >= 737280) return;
    int x = i % 96;
    int r = i / 96;
    int y = r % 96;
    int r2 = r / 96;
    int z = r2 % 16;
    int t = r2 / 16;
    const float* ft = fld + (size_t)t * 147456;
    int xp = min(x + 1, 95);
    int yr0 = y * 96, yr1 = min(y + 1, 95) * 96;
    int zr0 = z * 9216, zr1 = min(z + 1, 15) * 9216;
    float c000 = ft[zr0 + yr0 + x], c001 = ft[zr0 + yr0 + xp];
    float c010 = ft[zr0 + yr1 + x], c011 = ft[zr0 + yr1 + xp];
    float c100 = ft[zr1 + yr0 + x], c101 = ft[zr1 + yr0 + xp];
    float c110 = ft[zr1 + yr1 + x], c111 = ft[zr1 + yr1 + xp];
    Cell cl;
    cl.h0 = __floats2half2_rn(c000, c001);
    cl.h1 = __floats2half2_rn(c010, c011);
    cl.h2 = __floats2half2_rn(c100, c101);
    cl.h3 = __floats2half2_rn(c110, c111);
    cellp[i] = cl;
}

// 4 lanes per ray, 32 samples each. XCD-affinity block remap: blocks dispatch b%8 -> XCD,
// so XCD 0..4 serve one t each (2.36 MB, L2-resident); XCD 5..7 share the remainder.
__global__ __launch_bounds__(256) void render_kernel(
        const float* __restrict__ ro, const float* __restrict__ rd,
        const Cell* __restrict__ cellp,
        const float* __restrict__ nearA, const float* __restrict__ farA,
        const unsigned* __restrict__ loU, const unsigned* __restrict__ hiU,
        const float* __restrict__ dens_b, float* __restrict__ out) {
    int b = blockIdx.x;                 // 0..2559
    int b7 = b & 7, bhi = b >> 3;       // bhi 0..319
    int t, seg;
    if (b7 < 5) { t = b7; seg = bhi; }
    else { int j = (b7 - 5) * 320 + bhi; t = j / 192; seg = 320 + j % 192; }
    int c = threadIdx.x & 3;
    int ray = t * NRAYS + seg * 64 + (threadIdx.x >> 2);

    const float* o = ro + (size_t)ray * 3;
    const float* d = rd + (size_t)ray * 3;
    float ox = o[0], oy = o[1], oz = o[2];
    float dx = d[0], dy = d[1], dz = d[2];
    float nr = nearA[ray], fr = farA[ray];
    float span = fr - nr;
    const Cell* vt = cellp + (size_t)t * 147456;
    float db = dens_b[0];

    float step = span * 0.0078125f;
    float s  = fmaf((float)(c * 32), step, nr);
    float mid = s + 0.5f * step;
    float px = fmaf(dx, mid, ox);
    float py = fmaf(dy, mid, oy);
    float pz = fmaf(dz, mid, oz);
    float ddx = dx * step, ddy = dy * step, ddz = dz * step;

    float trans_acc = 0.f, num = 0.f, den = 0.f, A = 0.f;
    float trans = 1.f;
    int pidx = -1;
    float2 f00 = {0.f, 0.f}, f01 = {0.f, 0.f}, f10 = {0.f, 0.f}, f11 = {0.f, 0.f};
    (void)trans_acc;
    for (int kk = 0; kk < 32; ++kk) {
        float gx = fminf(fmaxf(px, 0.f), 1.f) * 95.f;
        float gy = fminf(fmaxf(py, 0.f), 1.f) * 95.f;
        float gz = fminf(fmaxf(pz, 0.f), 1.f) * 15.f;
        int x0 = min((int)gx, 94), y0 = min((int)gy, 94), z0 = min((int)gz, 14);
        float fx = gx - (float)x0, fy = gy - (float)y0, fz = gz - (float)z0;

        int idx = z0 * 9216 + y0 * 96 + x0;
        if (idx != pidx) {                    // exec-masked reload; ~1 dwordx4 per new cell
            pidx = idx;
            Cell cl = vt[idx];
            f00 = __half22float2(cl.h0);
            f01 = __half22float2(cl.h1);
            f10 = __half22float2(cl.h2);
            f11 = __half22float2(cl.h3);
        }

        float v00 = f00.x + fx * (f00.y - f00.x);
        float v01 = f01.x + fx * (f01.y - f01.x);
        float v10 = f10.x + fx * (f10.y - f10.x);
        float v11 = f11.x + fx * (f11.y - f11.x);
        float v0  = v00 + fy * (v01 - v00);
        float v1  = v10 + fy * (v11 - v10);
        float pre = v0 + fz * (v1 - v0) + db;

        float u = __expf(-fabsf(pre));
        float dens = fmaxf(pre, 0.f) + __logf(1.f + u);   // softplus
        float dd = dens * step;
        float ex = __expf(-dd);
        float w = (1.f - ex) * trans;
        num = fmaf(w, s, num);
        den += w;
        trans *= ex;
        A += dd;
        s += step; px += ddx; py += ddy; pz += ddz;
    }
    // prefix transmittance across the 4 chunks of this ray
    int lane = threadIdx.x & 63;
    int q = lane & ~3;
    float A0 = __shfl(A, q,     64);
    float A1 = __shfl(A, q + 1, 64);
    float A2 = __shfl(A, q + 2, 64);
    float P = 0.f;
    if (c > 0) P += A0;
    if (c > 1) P += A1;
    if (c > 2) P += A2;
    float sc = __expf(-P);
    float numc = num * sc;
    float denc = den * sc;
    numc += __shfl_xor(numc, 1, 64);
    numc += __shfl_xor(numc, 2, 64);
    denc += __shfl_xor(denc, 1, 64);
    denc += __shfl_xor(denc, 2, 64);
    if (c == 0) {
        float depth = numc / (denc + 1e-10f);
        float lo = __uint_as_float(loU[t]);
        float hi = __uint_as_float(hiU[t]);
        depth = fminf(fmaxf(depth, lo), hi);
        out[ray] = depth;
    }
}

extern "C" void kernel_launch(void* const* d_in, const int* in_sizes, int n_in,
                              void* d_out, int out_size, void* d_ws, size_t ws_size,
                              hipStream_t stream) {
    const float* vol = (const float*)d_in[0];   // [1,8,5,16,96,96]
    const float* ro  = (const float*)d_in[1];   // [5,32768,3]
    const float* rd  = (const float*)d_in[2];   // [5,32768,3]
    const float* cw  = (const float*)d_in[3];   // [128,128,3,3,3]
    const float* cb  = (const float*)d_in[4];   // [128]
    const float* dw  = (const float*)d_in[5];   // [8,1]
    const float* dbp = (const float*)d_in[6];   // [1]
    float* out = (float*)d_out;                 // [5,32768,1] f32

    // Region A (5,898,240 floats): volT during conv; fld (737,280) + cellp (2,949,120)
    // after conv (volT dead). part follows; misc at the end.
    const size_t A_FLOATS = 5898240;
    const size_t misc = 55296 + 32 + 163840 + 163840 + 16 + 64;
    const int SK = (ws_size >= (A_FLOATS + 12ull * 737280 + misc) * 4) ? 12 : 4;

    float* ws      = (float*)d_ws;
    float* volT    = ws;                          // A: [0 .. 5,898,240)
    float* fld     = ws;                          // A: [0 .. 737,280)  (after conv)
    Cell*  cellp   = (Cell*)(ws + 737280);        // A: [737,280 .. 3,686,400)
    float* part    = ws + A_FLOATS;               // SK * 737,280
    float* wR      = part + (size_t)SK * 737280;  // 55,296
    float* bR      = wR + 55296;                  // 16 (+pad 32)
    float* nearA   = bR + 32;                     // 163,840
    float* farA    = nearA + 163840;              // 163,840
    unsigned* loU  = (unsigned*)(farA + 163840);  // 8
    unsigned* hiU  = loU + 8;                     // 8

    hipLaunchKernelGGL(prep_w_kernel, dim3(216), dim3(256), 0, stream,
                       cw, cb, dw, wR, bR, loU, hiU);
    hipLaunchKernelGGL(transpose_vol_kernel, dim3(1440), dim3(256), 0, stream, vol, volT);
    hipLaunchKernelGGL(nearfar_kernel, dim3(640), dim3(256), 0, stream,
                       ro, rd, nearA, farA, loU, hiU);
    if (SK == 12) {
        hipLaunchKernelGGL(conv_kernel<1>, dim3(48, 5, 12), dim3(96, 2), 0, stream,
                           volT, wR, part);
    } else {
        hipLaunchKernelGGL(conv_kernel<3>, dim3(48, 5, 4), dim3(96, 2), 0, stream,
                           volT, wR, part);
    }
    hipLaunchKernelGGL(combine_kernel, dim3(720), dim3(256), 0, stream, part, bR, fld, SK);
    hipLaunchKernelGGL(pack_kernel, dim3(2880), dim3(256), 0, stream, fld, cellp);
    hipLaunchKernelGGL(render_kernel, dim3(2560), dim3(256), 0, stream,
                       ro, rd, cellp, nearA, farA, loU, hiU, dbp, out);
}